// Round 1
// baseline (12.118 us; speedup 1.0000x reference)
//
#include <hip/hip_runtime.h>
#include <math.h>

// QuanvolutionHybrid — analytic collapse of the 4-qubit circuit.
//
// Derivation: RZ = diagonal phase, CX = basis permutation, initial state is a
// real product state => probabilities are permutation of initial product probs;
// params drop out entirely. Two CX-chain layers map initial bits (a,b,c,d) to
// final (a, b, c^a, d^b), so PauliZ expectations per patch (x0,x1,x2,x3):
//   e0=cos(x0), e1=cos(x1), e2=cos(x0)cos(x2), e3=cos(x1)cos(x3).
// Then logits = feats @ W^T + b, out = log_softmax(logits).

#define BSZ 4096

__global__ __launch_bounds__(256) void quanv_fused_kernel(
    const float* __restrict__ x,     // [4096, 784]
    const float* __restrict__ W,     // [10, 784]
    const float* __restrict__ bias,  // [10]
    float* __restrict__ out)         // [4096, 10]
{
    __shared__ float sW[10 * 784];   // 31,360 B

    // Cooperative stage of W into LDS (coalesced float4).
    {
        const float4* Wv = (const float4*)W;
        float4* sWv = (float4*)sW;
        #pragma unroll
        for (int i = 0; i < 8; ++i) {
            int idx = threadIdx.x + i * 256;
            if (idx < 1960) sWv[idx] = Wv[idx];
        }
    }
    __syncthreads();

    const int wave = threadIdx.x >> 6;          // 0..3
    const int lane = threadIdx.x & 63;          // 0..63
    const int row  = blockIdx.x * 4 + wave;     // < 4096

    const float* __restrict__ xr = x + row * 784;

    float acc[10];
    #pragma unroll
    for (int o = 0; o < 10; ++o) acc[o] = 0.f;

    // 196 patches over 64 lanes: k = t*64 + lane
    #pragma unroll
    for (int t = 0; t < 4; ++t) {
        const int k = t * 64 + lane;
        if (k < 196) {
            const int r = k / 14;
            const int c = k - r * 14;
            const int base = r * 56 + c * 2;    // even -> 8B aligned
            const float2 a01 = *(const float2*)(xr + base);
            const float2 a23 = *(const float2*)(xr + base + 28);
            const float f0 = __cosf(a01.x);
            const float f1 = __cosf(a01.y);
            const float f2 = f0 * __cosf(a23.x);
            const float f3 = f1 * __cosf(a23.y);
            const float* wk = sW + k * 4;       // W[o][4k..4k+3] at wk + o*784
            #pragma unroll
            for (int o = 0; o < 10; ++o) {
                const float4 w4 = *(const float4*)(wk + o * 784); // 16B aligned (784%4==0)
                acc[o] = fmaf(f0, w4.x, acc[o]);
                acc[o] = fmaf(f1, w4.y, acc[o]);
                acc[o] = fmaf(f2, w4.z, acc[o]);
                acc[o] = fmaf(f3, w4.w, acc[o]);
            }
        }
    }

    // Wave-wide (64-lane) butterfly reduction of the 10 partial logits.
    #pragma unroll
    for (int o = 0; o < 10; ++o) {
        float v = acc[o];
        #pragma unroll
        for (int s = 32; s >= 1; s >>= 1) v += __shfl_xor(v, s, 64);
        acc[o] = v + bias[o];                   // bias: wave-uniform scalar load
    }

    // log_softmax over the 10 logits (computed redundantly on all lanes).
    float m = acc[0];
    #pragma unroll
    for (int o = 1; o < 10; ++o) m = fmaxf(m, acc[o]);
    float sum = 0.f;
    #pragma unroll
    for (int o = 0; o < 10; ++o) sum += __expf(acc[o] - m);
    const float lse = __logf(sum);

    if (lane < 10) out[row * 10 + lane] = acc[lane] - m - lse;
}

extern "C" void kernel_launch(void* const* d_in, const int* in_sizes, int n_in,
                              void* d_out, int out_size, void* d_ws, size_t ws_size,
                              hipStream_t stream) {
    const float* x    = (const float*)d_in[0];
    // d_in[1] = params — provably irrelevant to the output (phases/permutations only).
    const float* W    = (const float*)d_in[2];
    const float* bias = (const float*)d_in[3];
    float* out = (float*)d_out;

    dim3 grid(BSZ / 4);   // 1024 blocks, one wave per row
    dim3 block(256);
    quanv_fused_kernel<<<grid, block, 0, stream>>>(x, W, bias, out);
}

// Round 2
// 9.977 us; speedup vs baseline: 1.2146x; 1.2146x over previous
//
#include <hip/hip_runtime.h>
#include <math.h>

// QuanvolutionHybrid — analytic collapse of the 4-qubit circuit.
// RZ = diagonal phase, CX = basis permutation, initial state real product
// => params drop out. Final bits (a,b,c^a,d^b) give per-patch features:
//   e0=cos(x0), e1=cos(x1), e2=cos(x0)cos(x2), e3=cos(x1)cos(x3)
// logits = feats @ W^T + b; out = log_softmax(logits).
//
// v2: 32 lanes per row / 2 rows per wave (LDS same-address broadcast halves
// W-read cost), DPP-based cross-lane reduction (VALU pipe, zero LDS), serial
// softmax in lanes 31/63.

#define BSZ 4096

// v += value-from-DPP-shuffled-v ; masked-out / invalid-source lanes add 0.
#define DPP_ADD(v, ctrl, rmask)                                              \
    v += __int_as_float(__builtin_amdgcn_update_dpp(                         \
        0, __float_as_int(v), (ctrl), (rmask), 0xf, true))

__global__ __launch_bounds__(256) void quanv_fused_v2(
    const float* __restrict__ x,     // [4096, 784]
    const float* __restrict__ W,     // [10, 784]
    const float* __restrict__ bias,  // [10]
    float* __restrict__ out)         // [4096, 10]
{
    __shared__ float sW[10 * 784];   // 31,360 B

    // Cooperative stage of W into LDS (coalesced float4).
    {
        const float4* Wv = (const float4*)W;
        float4* sWv = (float4*)sW;
        #pragma unroll
        for (int i = 0; i < 8; ++i) {
            int idx = threadIdx.x + i * 256;
            if (idx < 1960) sWv[idx] = Wv[idx];
        }
    }
    __syncthreads();

    const int tid  = threadIdx.x;
    const int wave = tid >> 6;           // 0..3
    const int lane = tid & 63;
    const int h    = lane >> 5;          // which row of the pair
    const int kl   = lane & 31;          // patch-lane within the 32-group
    const int row  = blockIdx.x * 8 + wave * 2 + h;   // < 4096

    const float* __restrict__ xr = x + row * 784;

    float acc[10];
    #pragma unroll
    for (int o = 0; o < 10; ++o) acc[o] = 0.f;

    // 196 patches over 32 lanes: k = t*32 + kl, t = 0..6 (t=6: kl<4 only).
    #pragma unroll
    for (int t = 0; t < 7; ++t) {
        const int k = t * 32 + kl;
        if (t < 6 || kl < 4) {
            const int r = k / 14;
            const int c = k - r * 14;
            const int base = r * 56 + c * 2;          // even -> 8B aligned
            const float2 a01 = *(const float2*)(xr + base);
            const float2 a23 = *(const float2*)(xr + base + 28);
            const float f0 = __cosf(a01.x);
            const float f1 = __cosf(a01.y);
            const float f2 = f0 * __cosf(a23.x);
            const float f3 = f1 * __cosf(a23.y);
            // Both 32-lane halves read identical addresses -> LDS broadcast.
            const float* wk = sW + k * 4;
            #pragma unroll
            for (int o = 0; o < 10; ++o) {
                const float4 w4 = *(const float4*)(wk + o * 784);
                acc[o] = fmaf(f0, w4.x, acc[o]);
                acc[o] = fmaf(f1, w4.y, acc[o]);
                acc[o] = fmaf(f2, w4.z, acc[o]);
                acc[o] = fmaf(f3, w4.w, acc[o]);
            }
        }
    }

    // 32-lane DPP reduction per half: row_shr 1/2/4/8 then bcast15 into rows
    // 1,3. Totals land in lane 31 (row h=0) and lane 63 (row h=1). VALU-only.
    #pragma unroll
    for (int o = 0; o < 10; ++o) {
        float v = acc[o];
        DPP_ADD(v, 0x111, 0xf);   // row_shr:1
        DPP_ADD(v, 0x112, 0xf);   // row_shr:2
        DPP_ADD(v, 0x114, 0xf);   // row_shr:4
        DPP_ADD(v, 0x118, 0xf);   // row_shr:8  -> lane 15/31/47/63 hold 16-sums
        DPP_ADD(v, 0x142, 0xa);   // row_bcast15 into rows 1,3 -> lanes 31,63
        acc[o] = v;
    }

    // Finalize in the 2 total-holding lanes (31 and 63 — same instruction
    // stream, 2 active lanes per instruction).
    if (kl == 31) {
        float lg[10];
        float m = -1e30f;
        #pragma unroll
        for (int o = 0; o < 10; ++o) {
            lg[o] = acc[o] + bias[o];
            m = fmaxf(m, lg[o]);
        }
        float s = 0.f;
        #pragma unroll
        for (int o = 0; o < 10; ++o) s += __expf(lg[o] - m);
        const float lse = __logf(s) + m;
        float* orow = out + row * 10;
        #pragma unroll
        for (int o = 0; o < 10; ++o) orow[o] = lg[o] - lse;
    }
}

extern "C" void kernel_launch(void* const* d_in, const int* in_sizes, int n_in,
                              void* d_out, int out_size, void* d_ws, size_t ws_size,
                              hipStream_t stream) {
    const float* x    = (const float*)d_in[0];
    // d_in[1] = params — provably irrelevant (phases/permutations only).
    const float* W    = (const float*)d_in[2];
    const float* bias = (const float*)d_in[3];
    float* out = (float*)d_out;

    dim3 grid(BSZ / 8);   // 512 blocks: 4 waves/block, 2 rows/wave
    dim3 block(256);
    quanv_fused_v2<<<grid, block, 0, stream>>>(x, W, bias, out);
}